// Round 4
// baseline (164.150 us; speedup 1.0000x reference)
//
#include <hip/hip_runtime.h>

// Problem constants: m=4, h=16, t=1024, d=128, MAX_REL=128.
constexpr int D_DIM = 128;
constexpr int T_Q   = 1024;
constexpr int NPE   = 257;               // 2*MAX_REL + 1 pe rows
constexpr int WS_STRIDE = 260;           // floats per row in ws (16B-aligned rows)

// ============================ Kernel A: windows ============================
// Computes rel[row][j] = dot(Q[row], pe[j]) for j in [0,256] into ws.
constexpr int WAVES_A = 16;              // 1024 threads, 4 waves/SIMD
constexpr int RPW_A   = 8;
constexpr int THREADS_A = WAVES_A * 64;
constexpr int ROWS_PER_BLOCK_A = 256;

__global__ __launch_bounds__(THREADS_A, 4)
void rpe_windows(const float* __restrict__ Q,
                 const float* __restrict__ pe,
                 float* __restrict__ ws)
{
    // pe row j element d at pe_lds[j*128 + ((d + 4*j) & 127)] (see round-2/3 notes):
    // lane l owns j in {l, l+64, l+128, l+192}; one po=(d0+4l)&127 serves all 4
    // ds_read_b128; lanes 0..7 tile all 32 banks -> conflict-free; never wraps.
    __shared__ float pe_lds[NPE * 128];

    const int tid = threadIdx.x;
    const int w   = tid >> 6;
    const int l   = tid & 63;

    for (int flat = tid; flat < NPE * 128; flat += THREADS_A) {
        const int r = flat >> 7;
        const int d = flat & 127;
        pe_lds[r * 128 + ((d + 4 * r) & 127)] = pe[flat];
    }
    __syncthreads();

    const int rowBase = blockIdx.x * ROWS_PER_BLOCK_A;

    #pragma unroll 1
    for (int it = 0; it < ROWS_PER_BLOCK_A / (WAVES_A * RPW_A); ++it) {
        const int gRow0 = rowBase + it * (WAVES_A * RPW_A) + w * RPW_A;
        const float* __restrict__ Qw = Q + (size_t)gRow0 * D_DIM;

        float acc[RPW_A][4];
        #pragma unroll
        for (int r = 0; r < RPW_A; ++r)
            #pragma unroll
            for (int k = 0; k < 4; ++k) acc[r][k] = 0.f;

        #pragma unroll 2
        for (int d0 = 0; d0 < D_DIM; d0 += 4) {
            const int po = (d0 + 4 * l) & 127;
            const float4 p0 = *reinterpret_cast<const float4*>(&pe_lds[(l      ) * 128 + po]);
            const float4 p1 = *reinterpret_cast<const float4*>(&pe_lds[(l +  64) * 128 + po]);
            const float4 p2 = *reinterpret_cast<const float4*>(&pe_lds[(l + 128) * 128 + po]);
            const float4 p3 = *reinterpret_cast<const float4*>(&pe_lds[(l + 192) * 128 + po]);
            #pragma unroll
            for (int r = 0; r < RPW_A; ++r) {
                const float4 q = *reinterpret_cast<const float4*>(Qw + r * D_DIM + d0);
                acc[r][0] = fmaf(q.x, p0.x, acc[r][0]);
                acc[r][1] = fmaf(q.x, p1.x, acc[r][1]);
                acc[r][2] = fmaf(q.x, p2.x, acc[r][2]);
                acc[r][3] = fmaf(q.x, p3.x, acc[r][3]);
                acc[r][0] = fmaf(q.y, p0.y, acc[r][0]);
                acc[r][1] = fmaf(q.y, p1.y, acc[r][1]);
                acc[r][2] = fmaf(q.y, p2.y, acc[r][2]);
                acc[r][3] = fmaf(q.y, p3.y, acc[r][3]);
                acc[r][0] = fmaf(q.z, p0.z, acc[r][0]);
                acc[r][1] = fmaf(q.z, p1.z, acc[r][1]);
                acc[r][2] = fmaf(q.z, p2.z, acc[r][2]);
                acc[r][3] = fmaf(q.z, p3.z, acc[r][3]);
                acc[r][0] = fmaf(q.w, p0.w, acc[r][0]);
                acc[r][1] = fmaf(q.w, p1.w, acc[r][1]);
                acc[r][2] = fmaf(q.w, p2.w, acc[r][2]);
                acc[r][3] = fmaf(q.w, p3.w, acc[r][3]);
            }
        }

        // rel[256] per row: lanes split d, butterfly reduce
        float rel256[RPW_A];
        {
            const float pa = pe_lds[256 * 128 + l];        // (4*256)&127==0: unrotated
            const float pb = pe_lds[256 * 128 + l + 64];
            #pragma unroll
            for (int r = 0; r < RPW_A; ++r) {
                float part = Qw[r * D_DIM + l] * pa + Qw[r * D_DIM + l + 64] * pb;
                #pragma unroll
                for (int off = 32; off; off >>= 1)
                    part += __shfl_xor(part, off, 64);
                rel256[r] = part;
            }
        }

        // epilogue: coalesced dword stores of the window (fire-and-forget)
        #pragma unroll
        for (int r = 0; r < RPW_A; ++r) {
            float* wrow = ws + (size_t)(gRow0 + r) * WS_STRIDE;
            wrow[l      ] = acc[r][0];
            wrow[l +  64] = acc[r][1];
            wrow[l + 128] = acc[r][2];
            wrow[l + 192] = acc[r][3];
            if (l == 0) wrow[256] = rel256[r];
        }
    }
}

// ============================ Kernel B: expand =============================
// out[row][s] = win[clip(t-s+128, 0, 256)] — streaming, store-BW bound.
constexpr int WAVES_B = 4;               // 256 threads, 8 blocks/CU -> 32 waves/CU
constexpr int RPB     = 8;               // rows per wave

__global__ __launch_bounds__(WAVES_B * 64, 8)
void rpe_expand(const float* __restrict__ ws,
                float* __restrict__ out)
{
    __shared__ float wbuf[WAVES_B][2][WS_STRIDE];   // double-buffered per wave

    const int tid = threadIdx.x;
    const int w   = tid >> 6;
    const int l   = tid & 63;
    const int rowBase = (blockIdx.x * WAVES_B + w) * RPB;

    #pragma unroll 2
    for (int rr = 0; rr < RPB; ++rr) {
        const int row = rowBase + rr;
        const float* wrow = ws + (size_t)row * WS_STRIDE;
        const int buf = rr & 1;

        // per-lane b128 window load + broadcast scalars
        const float4 f  = *reinterpret_cast<const float4*>(wrow + 4 * l);
        const float r0   = wrow[0];      // all lanes same addr -> 1 request
        const float r256 = wrow[256];
        *reinterpret_cast<float4*>(&wbuf[w][buf][4 * l]) = f;
        asm volatile("s_waitcnt lgkmcnt(0)" ::: "memory");

        const int t = row & (T_Q - 1);
        float* orow = out + (size_t)row * T_Q;

        #pragma unroll
        for (int k = 0; k < 4; ++k) {
            const int s0 = 4 * l + 256 * k;
            const int j0 = t + 128 - s0;             // jraw at c=0 (max of group)
            float4 v;
            if (j0 <= 0) {                           // whole group -> rel[0]
                v = make_float4(r0, r0, r0, r0);
            } else if (j0 >= 259) {                  // whole group -> rel[256]
                v = make_float4(r256, r256, r256, r256);
            } else {                                 // middle: reversed gather
                float x[4];
                #pragma unroll
                for (int c = 0; c < 4; ++c) {
                    const int jr = j0 - c;
                    const int jc = jr < 0 ? 0 : (jr > 255 ? 255 : jr);
                    const float sv = wbuf[w][buf][jc];
                    x[c] = (jr >= 256) ? r256 : ((jr <= 0) ? r0 : sv);
                }
                v = make_float4(x[0], x[1], x[2], x[3]);
            }
            reinterpret_cast<float4*>(orow)[l + 64 * k] = v;
        }
    }
}

// ===================== Fallback: round-3 fused kernel ======================
constexpr int WAVES_F = 16;
constexpr int RPW_F   = 8;
constexpr int THREADS_F = WAVES_F * 64;
constexpr int ROWS_PER_BLOCK_F = 256;

__global__ __launch_bounds__(THREADS_F, 4)
void rpe_fused(const float* __restrict__ Q,
               const float* __restrict__ pe,
               float* __restrict__ out)
{
    __shared__ float pe_lds[NPE * 128];
    __shared__ float scratch[WAVES_F][256];

    const int tid = threadIdx.x;
    const int w   = tid >> 6;
    const int l   = tid & 63;

    for (int flat = tid; flat < NPE * 128; flat += THREADS_F) {
        const int r = flat >> 7;
        const int d = flat & 127;
        pe_lds[r * 128 + ((d + 4 * r) & 127)] = pe[flat];
    }
    __syncthreads();

    const int rowBase = blockIdx.x * ROWS_PER_BLOCK_F;

    #pragma unroll 1
    for (int it = 0; it < ROWS_PER_BLOCK_F / (WAVES_F * RPW_F); ++it) {
        const int gRow0 = rowBase + it * (WAVES_F * RPW_F) + w * RPW_F;
        const float* __restrict__ Qw = Q + (size_t)gRow0 * D_DIM;

        float acc[RPW_F][4];
        #pragma unroll
        for (int r = 0; r < RPW_F; ++r)
            #pragma unroll
            for (int k = 0; k < 4; ++k) acc[r][k] = 0.f;

        #pragma unroll 2
        for (int d0 = 0; d0 < D_DIM; d0 += 4) {
            const int po = (d0 + 4 * l) & 127;
            const float4 p0 = *reinterpret_cast<const float4*>(&pe_lds[(l      ) * 128 + po]);
            const float4 p1 = *reinterpret_cast<const float4*>(&pe_lds[(l +  64) * 128 + po]);
            const float4 p2 = *reinterpret_cast<const float4*>(&pe_lds[(l + 128) * 128 + po]);
            const float4 p3 = *reinterpret_cast<const float4*>(&pe_lds[(l + 192) * 128 + po]);
            #pragma unroll
            for (int r = 0; r < RPW_F; ++r) {
                const float4 q = *reinterpret_cast<const float4*>(Qw + r * D_DIM + d0);
                acc[r][0] = fmaf(q.x, p0.x, acc[r][0]);
                acc[r][1] = fmaf(q.x, p1.x, acc[r][1]);
                acc[r][2] = fmaf(q.x, p2.x, acc[r][2]);
                acc[r][3] = fmaf(q.x, p3.x, acc[r][3]);
                acc[r][0] = fmaf(q.y, p0.y, acc[r][0]);
                acc[r][1] = fmaf(q.y, p1.y, acc[r][1]);
                acc[r][2] = fmaf(q.y, p2.y, acc[r][2]);
                acc[r][3] = fmaf(q.y, p3.y, acc[r][3]);
                acc[r][0] = fmaf(q.z, p0.z, acc[r][0]);
                acc[r][1] = fmaf(q.z, p1.z, acc[r][1]);
                acc[r][2] = fmaf(q.z, p2.z, acc[r][2]);
                acc[r][3] = fmaf(q.z, p3.z, acc[r][3]);
                acc[r][0] = fmaf(q.w, p0.w, acc[r][0]);
                acc[r][1] = fmaf(q.w, p1.w, acc[r][1]);
                acc[r][2] = fmaf(q.w, p2.w, acc[r][2]);
                acc[r][3] = fmaf(q.w, p3.w, acc[r][3]);
            }
        }

        float rel256[RPW_F];
        {
            const float pa = pe_lds[256 * 128 + l];
            const float pb = pe_lds[256 * 128 + l + 64];
            #pragma unroll
            for (int r = 0; r < RPW_F; ++r) {
                float part = Qw[r * D_DIM + l] * pa + Qw[r * D_DIM + l + 64] * pb;
                #pragma unroll
                for (int off = 32; off; off >>= 1)
                    part += __shfl_xor(part, off, 64);
                rel256[r] = part;
            }
        }

        #pragma unroll 1
        for (int r = 0; r < RPW_F; ++r) {
            scratch[w][l      ] = acc[r][0];
            scratch[w][l +  64] = acc[r][1];
            scratch[w][l + 128] = acc[r][2];
            scratch[w][l + 192] = acc[r][3];
            asm volatile("s_waitcnt lgkmcnt(0)" ::: "memory");

            const int gRow = gRow0 + r;
            const int t = gRow & (T_Q - 1);
            float* orow = out + (size_t)gRow * T_Q;
            const float r256 = rel256[r];
            const float r0   = __builtin_amdgcn_readfirstlane(acc[r][0]);

            #pragma unroll
            for (int k = 0; k < 4; ++k) {
                const int s0 = 4 * l + 256 * k;
                const int j0 = t + 128 - s0;
                float4 v;
                if (j0 <= 0) {
                    v = make_float4(r0, r0, r0, r0);
                } else if (j0 >= 259) {
                    v = make_float4(r256, r256, r256, r256);
                } else {
                    float x[4];
                    #pragma unroll
                    for (int c = 0; c < 4; ++c) {
                        const int jr = j0 - c;
                        const int jc = jr < 0 ? 0 : (jr > 255 ? 255 : jr);
                        const float sv = scratch[w][jc];
                        x[c] = (jr >= 256) ? r256 : ((jr <= 0) ? r0 : sv);
                    }
                    v = make_float4(x[0], x[1], x[2], x[3]);
                }
                reinterpret_cast<float4*>(orow)[l + 64 * k] = v;
            }
        }
    }
}

extern "C" void kernel_launch(void* const* d_in, const int* in_sizes, int n_in,
                              void* d_out, int out_size, void* d_ws, size_t ws_size,
                              hipStream_t stream)
{
    const float* Q  = (const float*)d_in[0];
    // d_in[1] is K: only its shape matters (t_k = 1024), data unused.
    const float* pe = (const float*)d_in[2];
    float* out = (float*)d_out;

    const int total_rows = in_sizes[0] / D_DIM;            // m*h*t = 65536
    const size_t ws_needed = (size_t)total_rows * WS_STRIDE * sizeof(float); // 68.2 MB

    if (ws_size >= ws_needed) {
        float* ws = (float*)d_ws;
        const int gridA = total_rows / ROWS_PER_BLOCK_A;   // 256
        rpe_windows<<<gridA, THREADS_A, 0, stream>>>(Q, pe, ws);
        const int gridB = total_rows / (WAVES_B * RPB);    // 2048
        rpe_expand<<<gridB, WAVES_B * 64, 0, stream>>>(ws, out);
    } else {
        const int gridF = total_rows / ROWS_PER_BLOCK_F;   // 256
        rpe_fused<<<gridF, THREADS_F, 0, stream>>>(Q, pe, out);
    }
}

// Round 5
// 131.927 us; speedup vs baseline: 1.2443x; 1.2443x over previous
//
#include <hip/hip_runtime.h>

// Problem constants: m=4, h=16, t=1024, d=128, MAX_REL=128.
constexpr int D_DIM = 128;
constexpr int T_Q   = 1024;
constexpr int NPE   = 257;               // 2*MAX_REL + 1 pe rows
constexpr int WAVES = 8;                 // 512-thread block, 2 waves/SIMD (LDS-limited)
constexpr int RPW   = 8;                 // rows per wave per iteration
constexpr int BLOCK_THREADS  = WAVES * 64;
constexpr int ROWS_PER_BLOCK = 256;      // 65536 rows / 256 blocks

// pe row j element d at pe_lds[j*128 + ((d + 4*j) & 127)]:
// lane l owns j in {l, l+64, l+128, l+192}; 4*j mod 128 equal for all four, so one
// physical column po=(d0+4l)&127 serves all 4 ds_read_b128. Lanes 0..7 tile all 32
// banks -> conflict-free; po multiple of 4, <=124 -> float4 never wraps.
#define LOAD_P(BUF, STEP) {                                                        \
    const int po_ = (((STEP) * 4 + 4 * l) & 127);                                  \
    BUF[0] = *reinterpret_cast<const float4*>(&pe_lds[(l      ) * 128 + po_]);     \
    BUF[1] = *reinterpret_cast<const float4*>(&pe_lds[(l +  64) * 128 + po_]);     \
    BUF[2] = *reinterpret_cast<const float4*>(&pe_lds[(l + 128) * 128 + po_]);     \
    BUF[3] = *reinterpret_cast<const float4*>(&pe_lds[(l + 192) * 128 + po_]);     \
}

// q loads: all 64 lanes same address -> one 64B line, L1 broadcast (vmcnt domain;
// keeps SMEM off lgkmcnt so pe ds_reads get counted lgkm waits).
#define LOAD_Q(BUF, STEP) {                                                        \
    _Pragma("unroll")                                                              \
    for (int r_ = 0; r_ < RPW; ++r_)                                               \
        BUF[r_] = *reinterpret_cast<const float4*>(Qw + r_ * D_DIM + (STEP) * 4);  \
}

#define FMA_STEP(QB, PB) {                                                         \
    _Pragma("unroll")                                                              \
    for (int r_ = 0; r_ < RPW; ++r_) {                                             \
        acc[r_][0] = fmaf(QB[r_].x, PB[0].x, acc[r_][0]);                          \
        acc[r_][1] = fmaf(QB[r_].x, PB[1].x, acc[r_][1]);                          \
        acc[r_][2] = fmaf(QB[r_].x, PB[2].x, acc[r_][2]);                          \
        acc[r_][3] = fmaf(QB[r_].x, PB[3].x, acc[r_][3]);                          \
        acc[r_][0] = fmaf(QB[r_].y, PB[0].y, acc[r_][0]);                          \
        acc[r_][1] = fmaf(QB[r_].y, PB[1].y, acc[r_][1]);                          \
        acc[r_][2] = fmaf(QB[r_].y, PB[2].y, acc[r_][2]);                          \
        acc[r_][3] = fmaf(QB[r_].y, PB[3].y, acc[r_][3]);                          \
        acc[r_][0] = fmaf(QB[r_].z, PB[0].z, acc[r_][0]);                          \
        acc[r_][1] = fmaf(QB[r_].z, PB[1].z, acc[r_][1]);                          \
        acc[r_][2] = fmaf(QB[r_].z, PB[2].z, acc[r_][2]);                          \
        acc[r_][3] = fmaf(QB[r_].z, PB[3].z, acc[r_][3]);                          \
        acc[r_][0] = fmaf(QB[r_].w, PB[0].w, acc[r_][0]);                          \
        acc[r_][1] = fmaf(QB[r_].w, PB[1].w, acc[r_][1]);                          \
        acc[r_][2] = fmaf(QB[r_].w, PB[2].w, acc[r_][2]);                          \
        acc[r_][3] = fmaf(QB[r_].w, PB[3].w, acc[r_][3]);                          \
    }                                                                              \
}

// LDS: pe (rotated) 131.6 KB + per-wave rel scratch 8 KB = 139.8 KB -> 1 block/CU.
__global__ __launch_bounds__(BLOCK_THREADS, 2)   // 2 waves/EU -> <=256 VGPR budget
void rpe_fused(const float* __restrict__ Q,
               const float* __restrict__ pe,
               float* __restrict__ out)
{
    __shared__ float pe_lds[NPE * 128];
    __shared__ float scratch[WAVES][256];

    const int tid = threadIdx.x;
    const int w   = tid >> 6;
    const int l   = tid & 63;

    // ---- stage pe into LDS with rotation (once per block) ----
    for (int flat = tid; flat < NPE * 128; flat += BLOCK_THREADS) {
        const int r = flat >> 7;
        const int d = flat & 127;
        pe_lds[r * 128 + ((d + 4 * r) & 127)] = pe[flat];
    }
    __syncthreads();

    const int rowBase = blockIdx.x * ROWS_PER_BLOCK;

    #pragma unroll 1
    for (int it = 0; it < ROWS_PER_BLOCK / (WAVES * RPW); ++it) {   // 4 iters
        const int gRow0 = rowBase + it * (WAVES * RPW) + w * RPW;
        const float* __restrict__ Qw = Q + (size_t)gRow0 * D_DIM;

        float acc[RPW][4];
        #pragma unroll
        for (int r = 0; r < RPW; ++r)
            #pragma unroll
            for (int k = 0; k < 4; ++k) acc[r][k] = 0.f;

        // ---- software-pipelined main loop: 32 steps of d0=4*step, dbuf A/B ----
        float4 qA[RPW], qB[RPW], pA[4], pB[4];
        LOAD_P(pA, 0)
        LOAD_Q(qA, 0)
        #pragma unroll 1
        for (int s2 = 0; s2 < 16; ++s2) {
            const int s1 = 2 * s2 + 1;
            const int sn = (2 * s2 + 2) & 31;    // wraps to 0 on last iter (dead load, in-bounds)
            LOAD_P(pB, s1)
            LOAD_Q(qB, s1)
            FMA_STEP(qA, pA)                     // covers pB/qB in-flight latency
            LOAD_P(pA, sn)
            LOAD_Q(qA, sn)
            FMA_STEP(qB, pB)                     // covers pA/qA in-flight latency
        }

        // ---- rel[256] per row: lanes split d, 6-step butterfly reduce ----
        float rel256[RPW];
        {
            const float pa = pe_lds[256 * 128 + l];        // (4*256)&127==0: unrotated
            const float pb = pe_lds[256 * 128 + l + 64];
            #pragma unroll
            for (int r = 0; r < RPW; ++r) {
                float part = Qw[r * D_DIM + l] * pa + Qw[r * D_DIM + l + 64] * pb;
                #pragma unroll
                for (int off = 32; off; off >>= 1)
                    part += __shfl_xor(part, off, 64);
                rel256[r] = part;
            }
        }

        // ---- epilogue: spill window, region-split gather, coalesced stores ----
        #pragma unroll 1
        for (int r = 0; r < RPW; ++r) {
            scratch[w][l      ] = acc[r][0];     // window index j = l + 64k
            scratch[w][l +  64] = acc[r][1];
            scratch[w][l + 128] = acc[r][2];
            scratch[w][l + 192] = acc[r][3];
            asm volatile("s_waitcnt lgkmcnt(0)" ::: "memory");

            const int gRow = gRow0 + r;
            const int t = gRow & (T_Q - 1);
            float* orow = out + (size_t)gRow * T_Q;
            const float r256 = rel256[r];
            const float r0   = __builtin_amdgcn_readfirstlane(acc[r][0]); // rel[j=0]

            #pragma unroll
            for (int k = 0; k < 4; ++k) {
                const int s0 = 4 * l + 256 * k;
                const int j0 = t + 128 - s0;          // jraw at c=0 (max of the group)
                float4 v;
                if (j0 <= 0) {                         // whole group right-clipped -> rel[0]
                    v = make_float4(r0, r0, r0, r0);
                } else if (j0 >= 259) {                // whole group left-clipped -> rel[256]
                    v = make_float4(r256, r256, r256, r256);
                } else {                               // middle: reversed window gather
                    float x[4];
                    #pragma unroll
                    for (int c = 0; c < 4; ++c) {
                        const int jr = j0 - c;
                        const int jc = jr < 0 ? 0 : (jr > 255 ? 255 : jr);
                        const float sv = scratch[w][jc];
                        x[c] = (jr >= 256) ? r256 : ((jr <= 0) ? r0 : sv);
                    }
                    v = make_float4(x[0], x[1], x[2], x[3]);
                }
                reinterpret_cast<float4*>(orow)[l + 64 * k] = v;
            }
            // DS pipe is in-order per wave: next r's scratch writes cannot pass
            // this r's gather reads (which are lgkm-waited before the stores).
        }
    }
}

extern "C" void kernel_launch(void* const* d_in, const int* in_sizes, int n_in,
                              void* d_out, int out_size, void* d_ws, size_t ws_size,
                              hipStream_t stream)
{
    const float* Q  = (const float*)d_in[0];
    // d_in[1] is K: only its shape matters (t_k = 1024), data unused.
    const float* pe = (const float*)d_in[2];
    float* out = (float*)d_out;

    const int total_rows = in_sizes[0] / D_DIM;        // m*h*t = 65536
    const int grid = total_rows / ROWS_PER_BLOCK;      // 256 -> one block per CU
    rpe_fused<<<grid, BLOCK_THREADS, 0, stream>>>(Q, pe, out);
}

// Round 6
// 126.950 us; speedup vs baseline: 1.2930x; 1.0392x over previous
//
#include <hip/hip_runtime.h>

// Problem constants: m=4, h=16, t=1024, d=128, MAX_REL=128.
constexpr int D_DIM = 128;
constexpr int T_Q   = 1024;
constexpr int NPE   = 257;               // 2*MAX_REL + 1 pe rows
constexpr int WAVES = 8;                 // 512-thread block, 2 waves/SIMD (LDS-limited)
constexpr int RPW   = 8;                 // rows per wave per iteration
constexpr int BLOCK_THREADS  = WAVES * 64;
constexpr int ROWS_PER_BLOCK = 256;      // 65536 rows / 256 blocks; 4 iters/wave

// readlane: uniform lane index (SGPR), static register -> SGPR broadcast, no DS/memory.
#define RL(V, SRC) __uint_as_float(__builtin_amdgcn_readlane(__float_as_uint(V), (SRC)))

// Coalesced per-wave Q burst: 4 KB block (8 rows x 128 dims) in 4 dwordx4/lane.
// Lane l chunk c holds flat floats [c*256 + 4l .. +3] = row 2c+(l>=32), dims 4(l&31)..+3.
#define LOAD_BURST(BUF, IT) {                                                      \
    const float* qsrc_ = Q + (size_t)(rowBase + (IT) * (WAVES * RPW) + w * RPW) * D_DIM; \
    BUF[0] = *reinterpret_cast<const float4*>(qsrc_ +       4 * l);                \
    BUF[1] = *reinterpret_cast<const float4*>(qsrc_ + 256 + 4 * l);                \
    BUF[2] = *reinterpret_cast<const float4*>(qsrc_ + 512 + 4 * l);                \
    BUF[3] = *reinterpret_cast<const float4*>(qsrc_ + 768 + 4 * l);                \
}

// pe row j element d at pe_lds[j*128 + ((d + 4*j) & 127)]:
// lane l owns j in {l, l+64, l+128, l+192}; 4*j mod 128 equal for all four, so one
// physical column po=(4*sd+4l)&127 serves all 4 ds_read_b128. Lanes 0..7 tile all
// 32 banks -> conflict-free; po multiple of 4, <=124 -> float4 never wraps.
//
// One compute iteration: 32 steps (4 dims each); q[r][4sd+i] via readlane from
// QCUR[r>>1] component i, source lane 32*(r&1)+sd.
#define COMPUTE_ITER(IT, QCUR, QNXT, PREF, NIT) {                                  \
    const int gRow0 = rowBase + (IT) * (WAVES * RPW) + w * RPW;                    \
    const float* __restrict__ Qw = Q + (size_t)gRow0 * D_DIM;                      \
    float acc[RPW][4];                                                             \
    _Pragma("unroll")                                                              \
    for (int r = 0; r < RPW; ++r) {                                                \
        acc[r][0] = 0.f; acc[r][1] = 0.f; acc[r][2] = 0.f; acc[r][3] = 0.f;        \
    }                                                                              \
    _Pragma("unroll 2")                                                            \
    for (int sd = 0; sd < 32; ++sd) {                                              \
        const int po = (4 * sd + 4 * l) & 127;                                     \
        const float4 p0 = *reinterpret_cast<const float4*>(&pe_lds[(l      ) * 128 + po]); \
        const float4 p1 = *reinterpret_cast<const float4*>(&pe_lds[(l +  64) * 128 + po]); \
        const float4 p2 = *reinterpret_cast<const float4*>(&pe_lds[(l + 128) * 128 + po]); \
        const float4 p3 = *reinterpret_cast<const float4*>(&pe_lds[(l + 192) * 128 + po]); \
        _Pragma("unroll")                                                          \
        for (int r = 0; r < RPW; ++r) {                                            \
            const int src = ((r & 1) << 5) + sd;                                   \
            const float qx = RL(QCUR[r >> 1].x, src);                              \
            const float qy = RL(QCUR[r >> 1].y, src);                              \
            const float qz = RL(QCUR[r >> 1].z, src);                              \
            const float qw = RL(QCUR[r >> 1].w, src);                              \
            acc[r][0] = fmaf(qx, p0.x, acc[r][0]);                                 \
            acc[r][1] = fmaf(qx, p1.x, acc[r][1]);                                 \
            acc[r][2] = fmaf(qx, p2.x, acc[r][2]);                                 \
            acc[r][3] = fmaf(qx, p3.x, acc[r][3]);                                 \
            acc[r][0] = fmaf(qy, p0.y, acc[r][0]);                                 \
            acc[r][1] = fmaf(qy, p1.y, acc[r][1]);                                 \
            acc[r][2] = fmaf(qy, p2.y, acc[r][2]);                                 \
            acc[r][3] = fmaf(qy, p3.y, acc[r][3]);                                 \
            acc[r][0] = fmaf(qz, p0.z, acc[r][0]);                                 \
            acc[r][1] = fmaf(qz, p1.z, acc[r][1]);                                 \
            acc[r][2] = fmaf(qz, p2.z, acc[r][2]);                                 \
            acc[r][3] = fmaf(qz, p3.z, acc[r][3]);                                 \
            acc[r][0] = fmaf(qw, p0.w, acc[r][0]);                                 \
            acc[r][1] = fmaf(qw, p1.w, acc[r][1]);                                 \
            acc[r][2] = fmaf(qw, p2.w, acc[r][2]);                                 \
            acc[r][3] = fmaf(qw, p3.w, acc[r][3]);                                 \
        }                                                                          \
    }                                                                              \
    /* prefetch next iter's Q burst BEFORE the epilogue stores: in-order vmcnt   */ \
    /* retirement means next iter's wait completes without draining the stores. */ \
    if (PREF) LOAD_BURST(QNXT, NIT)                                                \
    /* rel[256] per row: lanes split d, butterfly reduce (Q rows are L1-hot).   */ \
    float rel256[RPW];                                                             \
    {                                                                              \
        const float pa = pe_lds[256 * 128 + l];        /* (4*256)&127==0 */        \
        const float pb = pe_lds[256 * 128 + l + 64];                               \
        _Pragma("unroll")                                                          \
        for (int r = 0; r < RPW; ++r) {                                            \
            float part = Qw[r * D_DIM + l] * pa + Qw[r * D_DIM + l + 64] * pb;     \
            _Pragma("unroll")                                                      \
            for (int off = 32; off; off >>= 1)                                     \
                part += __shfl_xor(part, off, 64);                                 \
            rel256[r] = part;                                                      \
        }                                                                          \
    }                                                                              \
    /* epilogue: spill window, region-split gather, coalesced b128 stores */       \
    _Pragma("unroll 1")                                                            \
    for (int r = 0; r < RPW; ++r) {                                                \
        scratch[w][l      ] = acc[r][0];     /* window j = l + 64k */              \
        scratch[w][l +  64] = acc[r][1];                                           \
        scratch[w][l + 128] = acc[r][2];                                           \
        scratch[w][l + 192] = acc[r][3];                                           \
        asm volatile("s_waitcnt lgkmcnt(0)" ::: "memory");                         \
        const int gRow = gRow0 + r;                                                \
        const int t = gRow & (T_Q - 1);                                            \
        float* orow = out + (size_t)gRow * T_Q;                                    \
        const float r256 = rel256[r];                                              \
        const float r0   = __builtin_amdgcn_readfirstlane(acc[r][0]); /* rel[0] */ \
        _Pragma("unroll")                                                          \
        for (int k = 0; k < 4; ++k) {                                              \
            const int s0 = 4 * l + 256 * k;                                        \
            const int j0 = t + 128 - s0;          /* jraw at c=0 (group max) */    \
            float4 v;                                                              \
            if (j0 <= 0) {                         /* all right-clipped -> rel[0] */ \
                v = make_float4(r0, r0, r0, r0);                                   \
            } else if (j0 >= 259) {                /* all left-clipped -> rel[256] */ \
                v = make_float4(r256, r256, r256, r256);                           \
            } else {                               /* reversed window gather */    \
                float x[4];                                                        \
                _Pragma("unroll")                                                  \
                for (int c = 0; c < 4; ++c) {                                      \
                    const int jr = j0 - c;                                         \
                    const int jc = jr < 0 ? 0 : (jr > 255 ? 255 : jr);             \
                    const float sv = scratch[w][jc];                               \
                    x[c] = (jr >= 256) ? r256 : ((jr <= 0) ? r0 : sv);             \
                }                                                                  \
                v = make_float4(x[0], x[1], x[2], x[3]);                           \
            }                                                                      \
            reinterpret_cast<float4*>(orow)[l + 64 * k] = v;                       \
        }                                                                          \
    }                                                                              \
}

// LDS: pe (rotated) 131.6 KB + per-wave rel scratch 8 KB = 139.8 KB -> 1 block/CU.
__global__ __launch_bounds__(BLOCK_THREADS, 2)   // 2 waves/EU -> <=256 VGPR budget
void rpe_fused(const float* __restrict__ Q,
               const float* __restrict__ pe,
               float* __restrict__ out)
{
    __shared__ float pe_lds[NPE * 128];
    __shared__ float scratch[WAVES][256];

    const int tid = threadIdx.x;
    const int w   = tid >> 6;
    const int l   = tid & 63;

    // ---- stage pe into LDS with rotation (once per block) ----
    for (int flat = tid; flat < NPE * 128; flat += BLOCK_THREADS) {
        const int r = flat >> 7;
        const int d = flat & 127;
        pe_lds[r * 128 + ((d + 4 * r) & 127)] = pe[flat];
    }
    __syncthreads();

    const int rowBase = blockIdx.x * ROWS_PER_BLOCK;

    // ---- 4 iterations, ping-pong Q burst buffers, statically unrolled ----
    float4 qbA[4], qbB[4];
    LOAD_BURST(qbA, 0)
    COMPUTE_ITER(0, qbA, qbB, 1, 1)
    COMPUTE_ITER(1, qbB, qbA, 1, 2)
    COMPUTE_ITER(2, qbA, qbB, 1, 3)
    COMPUTE_ITER(3, qbB, qbA, 0, 0)
}

extern "C" void kernel_launch(void* const* d_in, const int* in_sizes, int n_in,
                              void* d_out, int out_size, void* d_ws, size_t ws_size,
                              hipStream_t stream)
{
    const float* Q  = (const float*)d_in[0];
    // d_in[1] is K: only its shape matters (t_k = 1024), data unused.
    const float* pe = (const float*)d_in[2];
    float* out = (float*)d_out;

    const int total_rows = in_sizes[0] / D_DIM;        // m*h*t = 65536
    const int grid = total_rows / ROWS_PER_BLOCK;      // 256 -> one block per CU
    rpe_fused<<<grid, BLOCK_THREADS, 0, stream>>>(Q, pe, out);
}

// Round 7
// 106.514 us; speedup vs baseline: 1.5411x; 1.1919x over previous
//
#include <hip/hip_runtime.h>

// Problem constants: m=4, h=16, t=1024, d=128, MAX_REL=128.
constexpr int D_DIM = 128;
constexpr int T_Q   = 1024;
constexpr int NPE   = 257;               // 2*MAX_REL + 1 pe rows
constexpr int WAVES = 16;                // 1024-thread block -> 4 waves/SIMD
constexpr int RPW   = 8;                 // rows per wave per iteration
constexpr int BLOCK_THREADS  = WAVES * 64;
constexpr int ROWS_PER_BLOCK = 256;      // 65536 rows / 256 blocks; 2 iters/wave

// readlane: uniform lane index (SGPR), static register -> SGPR broadcast, no DS/memory.
#define RL(V, SRC) __uint_as_float(__builtin_amdgcn_readlane(__float_as_uint(V), (SRC)))

// Coalesced per-wave Q burst: 4 KB block (8 rows x 128 dims) in 4 dwordx4/lane.
// Lane l chunk c holds flat floats [c*256 + 4l .. +3] = row 2c+(l>=32), dims 4(l&31)..+3.
#define LOAD_BURST(BUF, IT) {                                                      \
    const float* qsrc_ = Q + (size_t)(rowBase + (IT) * (WAVES * RPW) + w * RPW) * D_DIM; \
    BUF[0] = *reinterpret_cast<const float4*>(qsrc_ +       4 * l);                \
    BUF[1] = *reinterpret_cast<const float4*>(qsrc_ + 256 + 4 * l);                \
    BUF[2] = *reinterpret_cast<const float4*>(qsrc_ + 512 + 4 * l);                \
    BUF[3] = *reinterpret_cast<const float4*>(qsrc_ + 768 + 4 * l);                \
}

// pe row j element d at pe_lds[j*128 + ((d + 4*j) & 127)]:
// lane l owns j in {l, l+64, l+128, l+192}; 4*j mod 128 equal for all four, so one
// physical column po=(4*sd+4l)&127 serves all 4 ds_read_b128. Lanes 0..7 tile all
// 32 banks -> conflict-free; po multiple of 4, <=124 -> float4 never wraps.
//
// One compute iteration: 32 steps (4 dims each); q[r][4sd+i] via readlane from
// QCUR[r>>1] component i, source lane 32*(r&1)+sd.
#define COMPUTE_ITER(IT, QCUR, QNXT, PREF, NIT) {                                  \
    const int gRow0 = rowBase + (IT) * (WAVES * RPW) + w * RPW;                    \
    const float* __restrict__ Qw = Q + (size_t)gRow0 * D_DIM;                      \
    float acc[RPW][4];                                                             \
    _Pragma("unroll")                                                              \
    for (int r = 0; r < RPW; ++r) {                                                \
        acc[r][0] = 0.f; acc[r][1] = 0.f; acc[r][2] = 0.f; acc[r][3] = 0.f;        \
    }                                                                              \
    _Pragma("unroll 2")                                                            \
    for (int sd = 0; sd < 32; ++sd) {                                              \
        const int po = (4 * sd + 4 * l) & 127;                                     \
        const float4 p0 = *reinterpret_cast<const float4*>(&pe_lds[(l      ) * 128 + po]); \
        const float4 p1 = *reinterpret_cast<const float4*>(&pe_lds[(l +  64) * 128 + po]); \
        const float4 p2 = *reinterpret_cast<const float4*>(&pe_lds[(l + 128) * 128 + po]); \
        const float4 p3 = *reinterpret_cast<const float4*>(&pe_lds[(l + 192) * 128 + po]); \
        _Pragma("unroll")                                                          \
        for (int r = 0; r < RPW; ++r) {                                            \
            const int src = ((r & 1) << 5) + sd;                                   \
            const float qx = RL(QCUR[r >> 1].x, src);                              \
            const float qy = RL(QCUR[r >> 1].y, src);                              \
            const float qz = RL(QCUR[r >> 1].z, src);                              \
            const float qw = RL(QCUR[r >> 1].w, src);                              \
            acc[r][0] = fmaf(qx, p0.x, acc[r][0]);                                 \
            acc[r][1] = fmaf(qx, p1.x, acc[r][1]);                                 \
            acc[r][2] = fmaf(qx, p2.x, acc[r][2]);                                 \
            acc[r][3] = fmaf(qx, p3.x, acc[r][3]);                                 \
            acc[r][0] = fmaf(qy, p0.y, acc[r][0]);                                 \
            acc[r][1] = fmaf(qy, p1.y, acc[r][1]);                                 \
            acc[r][2] = fmaf(qy, p2.y, acc[r][2]);                                 \
            acc[r][3] = fmaf(qy, p3.y, acc[r][3]);                                 \
            acc[r][0] = fmaf(qz, p0.z, acc[r][0]);                                 \
            acc[r][1] = fmaf(qz, p1.z, acc[r][1]);                                 \
            acc[r][2] = fmaf(qz, p2.z, acc[r][2]);                                 \
            acc[r][3] = fmaf(qz, p3.z, acc[r][3]);                                 \
            acc[r][0] = fmaf(qw, p0.w, acc[r][0]);                                 \
            acc[r][1] = fmaf(qw, p1.w, acc[r][1]);                                 \
            acc[r][2] = fmaf(qw, p2.w, acc[r][2]);                                 \
            acc[r][3] = fmaf(qw, p3.w, acc[r][3]);                                 \
        }                                                                          \
    }                                                                              \
    /* prefetch next iter's Q burst BEFORE the epilogue stores: loads are older   */ \
    /* than the stores in the vmcnt queue, so their wait drains no stores.       */ \
    if (PREF) LOAD_BURST(QNXT, NIT)                                                \
    /* rel[256] per row: lanes split d, butterfly reduce (Q rows are L1-hot).   */ \
    float rel256[RPW];                                                             \
    {                                                                              \
        const float pa = pe_lds[256 * 128 + l];        /* (4*256)&127==0 */        \
        const float pb = pe_lds[256 * 128 + l + 64];                               \
        _Pragma("unroll")                                                          \
        for (int r = 0; r < RPW; ++r) {                                            \
            float part = Qw[r * D_DIM + l] * pa + Qw[r * D_DIM + l + 64] * pb;     \
            _Pragma("unroll")                                                      \
            for (int off = 32; off; off >>= 1)                                     \
                part += __shfl_xor(part, off, 64);                                 \
            rel256[r] = part;                                                      \
        }                                                                          \
    }                                                                              \
    /* epilogue: spill window, region-split gather, coalesced b128 stores */       \
    _Pragma("unroll 1")                                                            \
    for (int r = 0; r < RPW; ++r) {                                                \
        scratch[w][l      ] = acc[r][0];     /* window j = l + 64k */              \
        scratch[w][l +  64] = acc[r][1];                                           \
        scratch[w][l + 128] = acc[r][2];                                           \
        scratch[w][l + 192] = acc[r][3];                                           \
        asm volatile("s_waitcnt lgkmcnt(0)" ::: "memory");                         \
        const int gRow = gRow0 + r;                                                \
        const int t = gRow & (T_Q - 1);                                            \
        float* orow = out + (size_t)gRow * T_Q;                                    \
        const float r256 = rel256[r];                                              \
        const float r0   = __builtin_amdgcn_readfirstlane(acc[r][0]); /* rel[0] */ \
        _Pragma("unroll")                                                          \
        for (int k = 0; k < 4; ++k) {                                              \
            const int s0 = 4 * l + 256 * k;                                        \
            const int j0 = t + 128 - s0;          /* jraw at c=0 (group max) */    \
            float4 v;                                                              \
            if (j0 <= 0) {                         /* all right-clipped -> rel[0] */ \
                v = make_float4(r0, r0, r0, r0);                                   \
            } else if (j0 >= 259) {                /* all left-clipped -> rel[256] */ \
                v = make_float4(r256, r256, r256, r256);                           \
            } else {                               /* reversed window gather */    \
                float x[4];                                                        \
                _Pragma("unroll")                                                  \
                for (int c = 0; c < 4; ++c) {                                      \
                    const int jr = j0 - c;                                         \
                    const int jc = jr < 0 ? 0 : (jr > 255 ? 255 : jr);             \
                    const float sv = scratch[w][jc];                               \
                    x[c] = (jr >= 256) ? r256 : ((jr <= 0) ? r0 : sv);             \
                }                                                                  \
                v = make_float4(x[0], x[1], x[2], x[3]);                           \
            }                                                                      \
            reinterpret_cast<float4*>(orow)[l + 64 * k] = v;                       \
        }                                                                          \
    }                                                                              \
}

// LDS: pe (rotated) 131.6 KB + per-wave rel scratch 16 KB = 147.9 KB -> 1 block/CU,
// 16 waves = 4 waves/SIMD.
__global__ __launch_bounds__(BLOCK_THREADS, 4)   // 4 waves/EU -> <=128 VGPR; need ~100
void rpe_fused(const float* __restrict__ Q,
               const float* __restrict__ pe,
               float* __restrict__ out)
{
    __shared__ float pe_lds[NPE * 128];
    __shared__ float scratch[WAVES][256];

    const int tid = threadIdx.x;
    const int w   = tid >> 6;
    const int l   = tid & 63;

    // ---- stage pe into LDS with rotation (once per block) ----
    for (int flat = tid; flat < NPE * 128; flat += BLOCK_THREADS) {
        const int r = flat >> 7;
        const int d = flat & 127;
        pe_lds[r * 128 + ((d + 4 * r) & 127)] = pe[flat];
    }
    __syncthreads();

    const int rowBase = blockIdx.x * ROWS_PER_BLOCK;

    // ---- 2 iterations, ping-pong Q burst buffers, statically unrolled ----
    float4 qbA[4], qbB[4];
    LOAD_BURST(qbA, 0)
    COMPUTE_ITER(0, qbA, qbB, 1, 1)
    COMPUTE_ITER(1, qbB, qbA, 0, 0)
}

extern "C" void kernel_launch(void* const* d_in, const int* in_sizes, int n_in,
                              void* d_out, int out_size, void* d_ws, size_t ws_size,
                              hipStream_t stream)
{
    const float* Q  = (const float*)d_in[0];
    // d_in[1] is K: only its shape matters (t_k = 1024), data unused.
    const float* pe = (const float*)d_in[2];
    float* out = (float*)d_out;

    const int total_rows = in_sizes[0] / D_DIM;        // m*h*t = 65536
    const int grid = total_rows / ROWS_PER_BLOCK;      // 256 -> one block per CU
    rpe_fused<<<grid, BLOCK_THREADS, 0, stream>>>(Q, pe, out);
}